// Round 1
// 2647.336 us; speedup vs baseline: 1.0030x; 1.0030x over previous
//
#include <hip/hip_runtime.h>

// ---------------------------------------------------------------------------
// HeteroSAGE 2-layer forward, restructured:
//   out_sage = agg @ (Wn@Wu_top) + x_dst @ (Ws@Wu_bot) + cf
//   cf = bn@Wu_top + bs@Wu_bot + bu
// agg via on-device CSR (hist -> scan -> scatter), register accumulation.
// bf16 MFMA (16x16x32) for all big GEMMs; fp32 bias/accum.
//
// R1: GEMM core upgraded to T3 "minimum 2-phase" double-buffered pipeline
//     (prefetch next K-tile before compute, single vmcnt(0)+barrier per
//     K-step AFTER compute) + bijective XCD-chunked block swizzle (T1)
//     with bn-fastest ordering so the 4 column-blocks of one A row-panel
//     co-reside in one XCD's L2.
// ---------------------------------------------------------------------------

typedef unsigned short ushort_t;
using short8 = __attribute__((ext_vector_type(8))) short;
using f32x4  = __attribute__((ext_vector_type(4))) float;

typedef __attribute__((address_space(3))) void lds_void;
typedef __attribute__((address_space(1))) void gbl_void;

__device__ __forceinline__ void gload16(const void* g, void* l) {
  __builtin_amdgcn_global_load_lds((gbl_void*)g, (lds_void*)l, 16, 0, 0);
}

__device__ __forceinline__ float bf2f(unsigned short u) {
  union { unsigned i; float f; } c; c.i = ((unsigned)u) << 16; return c.f;
}
__device__ __forceinline__ unsigned short f2bf(float f) {
  union { float f; unsigned i; } c; c.f = f;
  unsigned r = c.i + 0x7FFF + ((c.i >> 16) & 1);   // RTNE
  return (unsigned short)(r >> 16);
}
__device__ __forceinline__ unsigned pack2(float a, float b) {
  return (unsigned)f2bf(a) | ((unsigned)f2bf(b) << 16);
}

// ---------------------------------------------------------------------------
// GEMM core: C[M,N] = concat_K(A0,A1)[M,K] @ B[K,N] (+bias), B given as
// BT[N][K] bf16 (row stride ldb). 128x128 tile, BK=32, 256 thr = 4 waves,
// wave = 4x4 grid of 16x16x32 MFMA. MODE: 0 = f32 out (guard Mreal),
// 1 = lrelu->bf16 out (padded buffer, no guard), 2 = bf16 transpose-store.
// Double-buffered LDS, 2-phase software pipeline. Ktiles must be EVEN.
// ---------------------------------------------------------------------------
template <int MODE>
__device__ __forceinline__ void gemm_core(
    const ushort_t* __restrict__ A0, const ushort_t* __restrict__ A1,
    int lda, int ka0,
    const ushort_t* __restrict__ BT, int ldb,
    const float* __restrict__ bias,
    void* __restrict__ outp, int ldo, int Mreal, int Ktiles,
    int bm, int bn)
{
  __shared__ __align__(16) ushort_t lA[2][128 * 32];
  __shared__ __align__(16) ushort_t lB[2][128 * 32];
  const int tid = threadIdx.x;
  const int w = tid >> 6;
  const int l = tid & 63;
  const int srow = (l >> 2);        // 0..15
  const int scol = (l & 3) * 8;     // 0,8,16,24
  const int m_base = bm * 128;
  const int n_base = bn * 128;

  f32x4 acc[4][4] = {};

  // stage K-tile kt (BK=32) into LDS buffer `buf` — wave-uniform LDS dest,
  // per-lane global source (global_load_lds contract).
  auto stage = [&](int buf, int kt) {
    const int k0 = kt * 32;
    const ushort_t* As; int kk;
    if (k0 < ka0) { As = A0; kk = k0; } else { As = A1; kk = k0 - ka0; }
#pragma unroll
    for (int r = 0; r < 2; ++r) {
      const int row = r * 64 + w * 16 + srow;
      gload16(As + (size_t)(m_base + row) * lda + (kk + scol),
              &lA[buf][(r * 64 + w * 16) * 32]);
      gload16(BT + (size_t)(n_base + row) * ldb + (k0 + scol),
              &lB[buf][(r * 64 + w * 16) * 32]);
    }
  };

  const int wm0 = (w & 1) * 64;
  const int wn0 = (w >> 1) * 64;
  const int fr  = l & 15;
  const int fko = (l >> 4) * 8;

  auto compute = [&](int buf) {
    short8 a[4], b[4];
#pragma unroll
    for (int t = 0; t < 4; ++t) {
      a[t] = *(const short8*)&lA[buf][(wm0 + t * 16 + fr) * 32 + fko];
      b[t] = *(const short8*)&lB[buf][(wn0 + t * 16 + fr) * 32 + fko];
    }
#pragma unroll
    for (int mt = 0; mt < 4; ++mt)
#pragma unroll
      for (int nt = 0; nt < 4; ++nt)
        acc[mt][nt] = __builtin_amdgcn_mfma_f32_16x16x32_bf16(
            a[mt], b[nt], acc[mt][nt], 0, 0, 0);
  };

  // prologue: fill buf 0, drain, barrier
  stage(0, 0);
  __syncthreads();

  // main loop, 2 K-steps per iteration, compile-time buffer indices.
  // Invariant at loop top: buf0 holds tile kt (ready), buf1 free.
  for (int kt = 0; kt < Ktiles; kt += 2) {
    stage(1, kt + 1);            // prefetch (kt+1 < Ktiles since Ktiles even)
    compute(0);                  // ds_read buf0 + MFMA — hides stage latency
    __syncthreads();             // one vmcnt(0)+barrier: buf1 now ready
    if (kt + 2 < Ktiles) stage(0, kt + 2);
    compute(1);
    __syncthreads();
  }

  // epilogue: C/D layout col = lane&15, row = (lane>>4)*4 + reg  [m89-verified]
  const int quad = l >> 4;
  const int c15 = l & 15;
#pragma unroll
  for (int nt = 0; nt < 4; ++nt) {
    const int gn = n_base + wn0 + nt * 16 + c15;
    const float bv = (MODE == 2) ? 0.0f : bias[gn];
#pragma unroll
    for (int mt = 0; mt < 4; ++mt) {
#pragma unroll
      for (int r = 0; r < 4; ++r) {
        const int gm = m_base + wm0 + mt * 16 + quad * 4 + r;
        float v = acc[mt][nt][r] + bv;
        if (MODE == 0) {
          if (gm < Mreal) ((float*)outp)[(size_t)gm * ldo + gn] = v;
        } else if (MODE == 1) {
          float t = v > 0.0f ? v : 0.01f * v;
          ((ushort_t*)outp)[(size_t)gm * ldo + gn] = f2bf(t);
        } else {
          ((ushort_t*)outp)[(size_t)gn * ldo + gm] = f2bf(v);
        }
      }
    }
  }
}

struct GemmArgs {
  const ushort_t* A0; const ushort_t* A1; int lda; int ka0;
  const ushort_t* BT; int ldb; const float* bias;
  void* out; int ldo; int Mreal; int Ktiles;
};

// 1-D grid = Mtiles*4 blocks. bn fastest within the flat index, then the
// bijective chunked XCD swizzle (m204) so consecutive flat ids — i.e. the 4
// column-blocks sharing one A row-panel — land on the SAME XCD's L2.
template <int MODE>
__global__ __launch_bounds__(256) void gemm_kernel(GemmArgs g) {
  const int nwg = gridDim.x;
  const int orig = blockIdx.x;
  const int q = nwg >> 3, r = nwg & 7, x = orig & 7;
  const int swz = (x < r ? x * (q + 1) : r * (q + 1) + (x - r) * q) + (orig >> 3);
  const int bn = swz & 3;     // N = 512 -> 4 column tiles of 128
  const int bm = swz >> 2;
  gemm_core<MODE>(g.A0, g.A1, g.lda, g.ka0, g.BT, g.ldb, g.bias,
                  g.out, g.ldo, g.Mreal, g.Ktiles, bm, bn);
}

// Weight-fold GEMMs: z = sage*2 + half. C[512,512] = Whalf @ Wu_half,
// transpose-stored into WfT[sage][n][half*512 + k].
__global__ __launch_bounds__(256) void fold_gemm_kernel(
    const ushort_t* __restrict__ WnWs, const ushort_t* __restrict__ WuT,
    ushort_t* __restrict__ WfT)
{
  const int z = blockIdx.z, sage = z >> 1, half = z & 1;
  gemm_core<2>(WnWs + (size_t)sage * 524288 + half * 262144, nullptr, 512, (1 << 30),
               WuT + (size_t)sage * 524288 + half * 512, 1024, nullptr,
               WfT + (size_t)sage * 524288 + half * 512, 1024, 512, 16,
               blockIdx.x, blockIdx.y);
}

// ---------------------------------------------------------------------------
// lrelu + f32->bf16 cast, 4 elems/thread
// ---------------------------------------------------------------------------
__global__ void lrelu_cast_kernel(const float* __restrict__ x,
                                  ushort_t* __restrict__ h, int n4)
{
  const int i = blockIdx.x * 256 + threadIdx.x;
  if (i >= n4) return;
  const float4 v = ((const float4*)x)[i];
  float a = v.x > 0.f ? v.x : 0.01f * v.x;
  float b = v.y > 0.f ? v.y : 0.01f * v.y;
  float c = v.z > 0.f ? v.z : 0.01f * v.z;
  float d = v.w > 0.f ? v.w : 0.01f * v.w;
  uint2 o; o.x = pack2(a, b); o.y = pack2(c, d);
  ((uint2*)h)[i] = o;
}

// ---------------------------------------------------------------------------
// CSR build (both directions batched via blockIdx.y)
// ---------------------------------------------------------------------------
struct EdgeArgs {
  const int* src0; const int* dst0;   // dir 01: src in n0, dst in n1
  const int* src1; const int* dst1;   // dir 10
  int* cnt0; int* cnt1;
  int* indptr0; int* indptr1;
  int* fill0; int* fill1;
  int* esrc0; int* esrc1;
  int E; int nd0; int nd1;            // nd0 = N1 (dst of dir01), nd1 = N0
};

__global__ void hist_kernel(EdgeArgs ea) {
  const int dir = blockIdx.y;
  const int e = blockIdx.x * 256 + threadIdx.x;
  if (e >= ea.E) return;
  const int* dst = dir ? ea.dst1 : ea.dst0;
  int* cnt = dir ? ea.cnt1 : ea.cnt0;
  atomicAdd(&cnt[dst[e]], 1);
}

__global__ __launch_bounds__(1024) void scan_kernel(EdgeArgs ea) {
  const int dir = blockIdx.y;
  const int* cnt = dir ? ea.cnt1 : ea.cnt0;
  int* indptr = dir ? ea.indptr1 : ea.indptr0;
  int* fill = dir ? ea.fill1 : ea.fill0;
  const int n = dir ? ea.nd1 : ea.nd0;
  __shared__ int sd[1024];
  const int t = threadIdx.x;
  const int chunk = (n + 1023) >> 10;
  const int start = t * chunk;
  const int end = (start + chunk < n) ? (start + chunk) : n;
  int sum = 0;
  for (int i = start; i < end; ++i) sum += cnt[i];
  sd[t] = sum;
  __syncthreads();
  for (int off = 1; off < 1024; off <<= 1) {
    int v = (t >= off) ? sd[t - off] : 0;
    __syncthreads();
    sd[t] += v;
    __syncthreads();
  }
  int run = sd[t] - sum;   // exclusive prefix
  for (int i = start; i < end; ++i) { indptr[i] = run; fill[i] = run; run += cnt[i]; }
  if (t == 0) indptr[n] = ea.E;
}

__global__ void scatter_kernel(EdgeArgs ea) {
  const int dir = blockIdx.y;
  const int e = blockIdx.x * 256 + threadIdx.x;
  if (e >= ea.E) return;
  const int* dst = dir ? ea.dst1 : ea.dst0;
  const int* src = dir ? ea.src1 : ea.src0;
  int* fill = dir ? ea.fill1 : ea.fill0;
  int* esrc = dir ? ea.esrc1 : ea.esrc0;
  const int pos = atomicAdd(&fill[dst[e]], 1);
  esrc[pos] = src[e];
}

// ---------------------------------------------------------------------------
// mean aggregation: one wave per dst row; lane covers 8 bf16 (16B)
// ---------------------------------------------------------------------------
__device__ __forceinline__ void acc8(float* a, uint4 u) {
  a[0] += bf2f((unsigned short)(u.x & 0xffff)); a[1] += bf2f((unsigned short)(u.x >> 16));
  a[2] += bf2f((unsigned short)(u.y & 0xffff)); a[3] += bf2f((unsigned short)(u.y >> 16));
  a[4] += bf2f((unsigned short)(u.z & 0xffff)); a[5] += bf2f((unsigned short)(u.z >> 16));
  a[6] += bf2f((unsigned short)(u.w & 0xffff)); a[7] += bf2f((unsigned short)(u.w >> 16));
}

__global__ __launch_bounds__(256) void agg_kernel(
    const ushort_t* __restrict__ hsrc, const int* __restrict__ indptr,
    const int* __restrict__ esrc, ushort_t* __restrict__ out, int ndst)
{
  const int widx = blockIdx.x * 4 + (threadIdx.x >> 6);
  const int l = threadIdx.x & 63;
  if (widx >= ndst) return;
  const int s = indptr[widx], e = indptr[widx + 1];
  float a[8] = {0.f, 0.f, 0.f, 0.f, 0.f, 0.f, 0.f, 0.f};
  int i = s;
  for (; i + 1 < e; i += 2) {
    const int r0 = esrc[i], r1 = esrc[i + 1];
    const uint4 u0 = *(const uint4*)(hsrc + (size_t)r0 * 512 + l * 8);
    const uint4 u1 = *(const uint4*)(hsrc + (size_t)r1 * 512 + l * 8);
    acc8(a, u0); acc8(a, u1);
  }
  if (i < e) {
    const uint4 u = *(const uint4*)(hsrc + (size_t)esrc[i] * 512 + l * 8);
    acc8(a, u);
  }
  const int deg = e - s;
  const float sc = 1.0f / (float)(deg > 1 ? deg : 1);
  uint4 o;
  o.x = pack2(a[0] * sc, a[1] * sc); o.y = pack2(a[2] * sc, a[3] * sc);
  o.z = pack2(a[4] * sc, a[5] * sc); o.w = pack2(a[6] * sc, a[7] * sc);
  *(uint4*)(out + (size_t)widx * 512 + l * 8) = o;
}

// ---------------------------------------------------------------------------
// weight casts: y-dim selects matrix (0=Wn, 1=Ws direct; 2=Wu transpose-cast)
// ---------------------------------------------------------------------------
struct CastArgs { const float* Wn[4]; const float* Ws[4]; const float* Wu[4]; };

__global__ void cast_all_kernel(CastArgs ca, ushort_t* __restrict__ WnWs,
                                ushort_t* __restrict__ WuT)
{
  const int sage = blockIdx.z;
  const int type = blockIdx.y;
  const int idx = blockIdx.x * 256 + threadIdx.x;
  if (type < 2) {
    if (idx >= 512 * 512) return;
    const float* src = type == 0 ? ca.Wn[sage] : ca.Ws[sage];
    WnWs[(size_t)sage * 524288 + type * 262144 + idx] = f2bf(src[idx]);
  } else {
    if (idx >= 1024 * 512) return;
    const int k = idx >> 9, n = idx & 511;     // read Wu[k][n] coalesced
    WuT[(size_t)sage * 524288 + (size_t)n * 1024 + k] = f2bf(ca.Wu[sage][idx]);
  }
}

struct BiasArgs { const float* bn[4]; const float* bs[4];
                  const float* Wu[4]; const float* bu[4]; };

__global__ void bias_fold_kernel(BiasArgs ba, float* __restrict__ cf) {
  const int sage = blockIdx.y;
  const int n = blockIdx.x * 256 + threadIdx.x;   // grid.x = 2 -> n in [0,512)
  const float* Wu = ba.Wu[sage];
  const float* bn = ba.bn[sage];
  const float* bs = ba.bs[sage];
  float s = ba.bu[sage][n];
  for (int j = 0; j < 512; ++j)
    s += bn[j] * Wu[(size_t)j * 512 + n] + bs[j] * Wu[(size_t)(512 + j) * 512 + n];
  cf[sage * 512 + n] = s;
}

// ---------------------------------------------------------------------------
extern "C" void kernel_launch(void* const* d_in, const int* in_sizes, int n_in,
                              void* d_out, int out_size, void* d_ws, size_t ws_size,
                              hipStream_t stream)
{
  const int Dm = 512;
  const int N0 = in_sizes[0] / Dm;              // 100000
  const int N1 = in_sizes[1] / Dm;              // 100000
  const int E  = in_sizes[2] / 2;               // 1000000
  const int NMAX = N0 > N1 ? N0 : N1;
  const int MP = ((NMAX + 127) / 128) * 128;    // 100096
  const int Mtiles = MP / 128;

  auto al = [](size_t x) { return (x + 255) & ~(size_t)255; };
  const size_t BIG = (size_t)MP * 512 * sizeof(ushort_t);   // 102.5 MB

  char* p = (char*)d_ws;
  ushort_t* h0 = (ushort_t*)p; p += BIG;        // lrelu(x_n0) / later agg01'
  ushort_t* h1 = (ushort_t*)p; p += BIG;        // lrelu(x_n1) / later agg10'
  ushort_t* bA = (ushort_t*)p; p += BIG;        // agg01 -> later h0n
  ushort_t* bB = (ushort_t*)p; p += BIG;        // agg10
  ushort_t* bC = (ushort_t*)p; p += BIG;        // h1n
  ushort_t* WnWs = (ushort_t*)p; p += al((size_t)4 * 524288 * 2);
  ushort_t* WuT  = (ushort_t*)p; p += al((size_t)4 * 524288 * 2);
  ushort_t* WfT  = (ushort_t*)p; p += al((size_t)4 * 524288 * 2);
  float* cf = (float*)p; p += al(4 * 512 * sizeof(float));
  char* cnt_base = p;
  int* cnt0 = (int*)p; p += al((size_t)N1 * 4);
  int* cnt1 = (int*)p; p += al((size_t)N0 * 4);
  const size_t cnt_bytes = (size_t)(p - cnt_base);
  int* ip0 = (int*)p; p += al((size_t)(N1 + 1) * 4);
  int* ip1 = (int*)p; p += al((size_t)(N0 + 1) * 4);
  int* fl0 = (int*)p; p += al((size_t)N1 * 4);
  int* fl1 = (int*)p; p += al((size_t)N0 * 4);
  int* es0 = (int*)p; p += al((size_t)E * 4);
  int* es1 = (int*)p; p += al((size_t)E * 4);
  if ((size_t)(p - (char*)d_ws) > ws_size) return;   // fail visibly, no corruption

  const float* x0 = (const float*)d_in[0];
  const float* x1 = (const float*)d_in[1];
  const int* ei01 = (const int*)d_in[2];
  const int* ei10 = (const int*)d_in[3];

  CastArgs ca; BiasArgs ba;
  for (int s = 0; s < 4; ++s) {
    const int base = 4 + 6 * s;   // s0=l1_01, s1=l1_10, s2=l2_01, s3=l2_10
    ca.Wn[s] = (const float*)d_in[base + 0];
    ba.bn[s] = (const float*)d_in[base + 1];
    ca.Ws[s] = (const float*)d_in[base + 2];
    ba.bs[s] = (const float*)d_in[base + 3];
    ca.Wu[s] = (const float*)d_in[base + 4];
    ba.Wu[s] = ca.Wu[s];
    ba.bu[s] = (const float*)d_in[base + 5];
  }

  EdgeArgs ea;
  ea.src0 = ei01; ea.dst0 = ei01 + E;
  ea.src1 = ei10; ea.dst1 = ei10 + E;
  ea.cnt0 = cnt0; ea.cnt1 = cnt1;
  ea.indptr0 = ip0; ea.indptr1 = ip1;
  ea.fill0 = fl0; ea.fill1 = fl1;
  ea.esrc0 = es0; ea.esrc1 = es1;
  ea.E = E; ea.nd0 = N1; ea.nd1 = N0;

  // ---- input prep + CSR build ----
  hipMemsetAsync(cnt_base, 0, cnt_bytes, stream);
  lrelu_cast_kernel<<<dim3((N0 * Dm / 4 + 255) / 256), 256, 0, stream>>>(x0, h0, N0 * Dm / 4);
  lrelu_cast_kernel<<<dim3((N1 * Dm / 4 + 255) / 256), 256, 0, stream>>>(x1, h1, N1 * Dm / 4);
  hist_kernel<<<dim3((E + 255) / 256, 2), 256, 0, stream>>>(ea);
  scan_kernel<<<dim3(1, 2), 1024, 0, stream>>>(ea);
  scatter_kernel<<<dim3((E + 255) / 256, 2), 256, 0, stream>>>(ea);

  // ---- weight folding ----
  cast_all_kernel<<<dim3(2048, 3, 4), 256, 0, stream>>>(ca, WnWs, WuT);
  fold_gemm_kernel<<<dim3(4, 4, 8), 256, 0, stream>>>(WnWs, WuT, WfT);
  bias_fold_kernel<<<dim3(2, 4), 256, 0, stream>>>(ba, cf);

  // ---- layer 1 ----
  agg_kernel<<<dim3((N1 + 3) / 4), 256, 0, stream>>>(h0, ip0, es0, bA, N1); // agg01
  agg_kernel<<<dim3((N0 + 3) / 4), 256, 0, stream>>>(h1, ip1, es1, bB, N0); // agg10

  GemmArgs g;
  g.lda = 512; g.ka0 = 512; g.ldb = 1024; g.Ktiles = 32; g.ldo = 512;
  const int NWG = Mtiles * 4;   // 1-D grid, bn fastest + XCD chunk swizzle
  // o1 = [agg01 | h1] @ Wf(l1_01) -> lrelu -> bC (h1n)
  g.A0 = bA; g.A1 = h1; g.BT = WfT + 0 * 524288; g.bias = cf + 0;
  g.out = bC; g.Mreal = N1;
  gemm_kernel<1><<<dim3(NWG), 256, 0, stream>>>(g);
  // o0 = [agg10 | h0] @ Wf(l1_10) -> lrelu -> bA (h0n)
  g.A0 = bB; g.A1 = h0; g.BT = WfT + 1 * 524288; g.bias = cf + 512;
  g.out = bA; g.Mreal = N0;
  gemm_kernel<1><<<dim3(NWG), 256, 0, stream>>>(g);

  // ---- layer 2 ----
  agg_kernel<<<dim3((N1 + 3) / 4), 256, 0, stream>>>(bA, ip0, es0, h0, N1); // agg01'
  agg_kernel<<<dim3((N0 + 3) / 4), 256, 0, stream>>>(bC, ip1, es1, h1, N0); // agg10'

  // o1_final = [agg01' | h1n] @ Wf(l2_01) -> d_out + N0*512 (f32)
  g.A0 = h0; g.A1 = bC; g.BT = WfT + 2 * 524288; g.bias = cf + 1024;
  g.out = (float*)d_out + (size_t)N0 * 512; g.Mreal = N1;
  gemm_kernel<0><<<dim3(NWG), 256, 0, stream>>>(g);
  // o0_final = [agg10' | h0n] @ Wf(l2_10) -> d_out (f32)
  g.A0 = h1; g.A1 = bA; g.BT = WfT + 3 * 524288; g.bias = cf + 1536;
  g.out = (float*)d_out; g.Mreal = N0;
  gemm_kernel<0><<<dim3(NWG), 256, 0, stream>>>(g);
}

// Round 2
// 2509.851 us; speedup vs baseline: 1.0580x; 1.0548x over previous
//
#include <hip/hip_runtime.h>

// ---------------------------------------------------------------------------
// HeteroSAGE 2-layer forward, restructured:
//   out_sage = agg @ (Wn@Wu_top) + x_dst @ (Ws@Wu_bot) + cf
//   cf = bn@Wu_top + bs@Wu_bot + bu
// agg via on-device CSR (hist -> scan -> scatter), register accumulation.
// bf16 MFMA (16x16x32) for all big GEMMs; fp32 bias/accum.
//
// R2: GEMM 128x128 tile now uses 512 threads / 8 waves (2M x 4N of 64x32
//     each) to raise resident waves/SIMD ~2.5x (R0/R1 showed Occupancy 30%,
//     MfmaUtil 16% -> latency-bound). 2-phase dbuf schedule kept verbatim.
//     Agg gather unrolled to 4 edges in flight (MLP).
// ---------------------------------------------------------------------------

typedef unsigned short ushort_t;
using short8 = __attribute__((ext_vector_type(8))) short;
using f32x4  = __attribute__((ext_vector_type(4))) float;

typedef __attribute__((address_space(3))) void lds_void;
typedef __attribute__((address_space(1))) void gbl_void;

__device__ __forceinline__ void gload16(const void* g, void* l) {
  __builtin_amdgcn_global_load_lds((gbl_void*)g, (lds_void*)l, 16, 0, 0);
}

__device__ __forceinline__ float bf2f(unsigned short u) {
  union { unsigned i; float f; } c; c.i = ((unsigned)u) << 16; return c.f;
}
__device__ __forceinline__ unsigned short f2bf(float f) {
  union { float f; unsigned i; } c; c.f = f;
  unsigned r = c.i + 0x7FFF + ((c.i >> 16) & 1);   // RTNE
  return (unsigned short)(r >> 16);
}
__device__ __forceinline__ unsigned pack2(float a, float b) {
  return (unsigned)f2bf(a) | ((unsigned)f2bf(b) << 16);
}

// ---------------------------------------------------------------------------
// GEMM core: C[M,N] = concat_K(A0,A1)[M,K] @ B[K,N] (+bias), B given as
// BT[N][K] bf16 (row stride ldb). 128x128 tile, BK=32, 512 thr = 8 waves,
// wave = 4x2 grid of 16x16x32 MFMA (64 rows x 32 cols per wave).
// MODE: 0 = f32 out (guard Mreal), 1 = lrelu->bf16 out (padded, no guard),
// 2 = bf16 transpose-store. Double-buffered LDS, 2-phase pipeline.
// Ktiles must be EVEN.
// ---------------------------------------------------------------------------
template <int MODE>
__device__ __forceinline__ void gemm_core(
    const ushort_t* __restrict__ A0, const ushort_t* __restrict__ A1,
    int lda, int ka0,
    const ushort_t* __restrict__ BT, int ldb,
    const float* __restrict__ bias,
    void* __restrict__ outp, int ldo, int Mreal, int Ktiles,
    int bm, int bn)
{
  __shared__ __align__(16) ushort_t lA[2][128 * 32];
  __shared__ __align__(16) ushort_t lB[2][128 * 32];
  const int tid = threadIdx.x;
  const int w = tid >> 6;           // 0..7
  const int l = tid & 63;
  const int srow = tid >> 2;        // 0..127 (4 threads per row)
  const int scol = (tid & 3) * 8;   // 0,8,16,24
  const int m_base = bm * 128;
  const int n_base = bn * 128;

  f32x4 acc[4][2] = {};

  // stage K-tile kt (BK=32) into LDS buffer `buf`. Per-wave LDS dest is
  // uniform-base + lane*16 (dest byte = tid*16), global src per-lane.
  auto stage = [&](int buf, int kt) {
    const int k0 = kt * 32;
    const ushort_t* As; int kk;
    if (k0 < ka0) { As = A0; kk = k0; } else { As = A1; kk = k0 - ka0; }
    gload16(As + (size_t)(m_base + srow) * lda + (kk + scol),
            &lA[buf][srow * 32 + scol]);
    gload16(BT + (size_t)(n_base + srow) * ldb + (k0 + scol),
            &lB[buf][srow * 32 + scol]);
  };

  const int wm0 = (w & 1) * 64;     // 2 wave-rows of 64
  const int wn0 = (w >> 1) * 32;    // 4 wave-cols of 32
  const int fr  = l & 15;
  const int fko = (l >> 4) * 8;

  auto compute = [&](int buf) {
    short8 a[4], b[2];
#pragma unroll
    for (int t = 0; t < 4; ++t)
      a[t] = *(const short8*)&lA[buf][(wm0 + t * 16 + fr) * 32 + fko];
#pragma unroll
    for (int t = 0; t < 2; ++t)
      b[t] = *(const short8*)&lB[buf][(wn0 + t * 16 + fr) * 32 + fko];
#pragma unroll
    for (int mt = 0; mt < 4; ++mt)
#pragma unroll
      for (int nt = 0; nt < 2; ++nt)
        acc[mt][nt] = __builtin_amdgcn_mfma_f32_16x16x32_bf16(
            a[mt], b[nt], acc[mt][nt], 0, 0, 0);
  };

  // prologue: fill buf 0, drain, barrier
  stage(0, 0);
  __syncthreads();

  // 2 K-steps per iteration, compile-time buffer indices.
  for (int kt = 0; kt < Ktiles; kt += 2) {
    stage(1, kt + 1);            // prefetch next tile first
    compute(0);                  // hides stage latency under MFMA
    __syncthreads();             // single vmcnt(0)+barrier per K-step
    if (kt + 2 < Ktiles) stage(0, kt + 2);
    compute(1);
    __syncthreads();
  }

  // epilogue: C/D layout col = lane&15, row = (lane>>4)*4 + reg  [m89-verified]
  const int quad = l >> 4;
  const int c15 = l & 15;
#pragma unroll
  for (int nt = 0; nt < 2; ++nt) {
    const int gn = n_base + wn0 + nt * 16 + c15;
    const float bv = (MODE == 2) ? 0.0f : bias[gn];
#pragma unroll
    for (int mt = 0; mt < 4; ++mt) {
#pragma unroll
      for (int r = 0; r < 4; ++r) {
        const int gm = m_base + wm0 + mt * 16 + quad * 4 + r;
        float v = acc[mt][nt][r] + bv;
        if (MODE == 0) {
          if (gm < Mreal) ((float*)outp)[(size_t)gm * ldo + gn] = v;
        } else if (MODE == 1) {
          float t = v > 0.0f ? v : 0.01f * v;
          ((ushort_t*)outp)[(size_t)gm * ldo + gn] = f2bf(t);
        } else {
          ((ushort_t*)outp)[(size_t)gn * ldo + gm] = f2bf(v);
        }
      }
    }
  }
}

struct GemmArgs {
  const ushort_t* A0; const ushort_t* A1; int lda; int ka0;
  const ushort_t* BT; int ldb; const float* bias;
  void* out; int ldo; int Mreal; int Ktiles;
};

// 1-D grid = Mtiles*4 blocks (divisible by 8). bn fastest within the flat
// index, then the bijective chunked XCD swizzle (m204) so the 4 column-blocks
// sharing one A row-panel co-reside in one XCD's L2.
template <int MODE>
__global__ __launch_bounds__(512, 4) void gemm_kernel(GemmArgs g) {
  const int nwg = gridDim.x;
  const int orig = blockIdx.x;
  const int q = nwg >> 3, r = nwg & 7, x = orig & 7;
  const int swz = (x < r ? x * (q + 1) : r * (q + 1) + (x - r) * q) + (orig >> 3);
  const int bn = swz & 3;     // N = 512 -> 4 column tiles of 128
  const int bm = swz >> 2;
  gemm_core<MODE>(g.A0, g.A1, g.lda, g.ka0, g.BT, g.ldb, g.bias,
                  g.out, g.ldo, g.Mreal, g.Ktiles, bm, bn);
}

// Weight-fold GEMMs: z = sage*2 + half. C[512,512] = Whalf @ Wu_half,
// transpose-stored into WfT[sage][n][half*512 + k].
__global__ __launch_bounds__(512, 4) void fold_gemm_kernel(
    const ushort_t* __restrict__ WnWs, const ushort_t* __restrict__ WuT,
    ushort_t* __restrict__ WfT)
{
  const int z = blockIdx.z, sage = z >> 1, half = z & 1;
  gemm_core<2>(WnWs + (size_t)sage * 524288 + half * 262144, nullptr, 512, (1 << 30),
               WuT + (size_t)sage * 524288 + half * 512, 1024, nullptr,
               WfT + (size_t)sage * 524288 + half * 512, 1024, 512, 16,
               blockIdx.x, blockIdx.y);
}

// ---------------------------------------------------------------------------
// lrelu + f32->bf16 cast, 4 elems/thread
// ---------------------------------------------------------------------------
__global__ void lrelu_cast_kernel(const float* __restrict__ x,
                                  ushort_t* __restrict__ h, int n4)
{
  const int i = blockIdx.x * 256 + threadIdx.x;
  if (i >= n4) return;
  const float4 v = ((const float4*)x)[i];
  float a = v.x > 0.f ? v.x : 0.01f * v.x;
  float b = v.y > 0.f ? v.y : 0.01f * v.y;
  float c = v.z > 0.f ? v.z : 0.01f * v.z;
  float d = v.w > 0.f ? v.w : 0.01f * v.w;
  uint2 o; o.x = pack2(a, b); o.y = pack2(c, d);
  ((uint2*)h)[i] = o;
}

// ---------------------------------------------------------------------------
// CSR build (both directions batched via blockIdx.y)
// ---------------------------------------------------------------------------
struct EdgeArgs {
  const int* src0; const int* dst0;   // dir 01: src in n0, dst in n1
  const int* src1; const int* dst1;   // dir 10
  int* cnt0; int* cnt1;
  int* indptr0; int* indptr1;
  int* fill0; int* fill1;
  int* esrc0; int* esrc1;
  int E; int nd0; int nd1;            // nd0 = N1 (dst of dir01), nd1 = N0
};

__global__ void hist_kernel(EdgeArgs ea) {
  const int dir = blockIdx.y;
  const int e = blockIdx.x * 256 + threadIdx.x;
  if (e >= ea.E) return;
  const int* dst = dir ? ea.dst1 : ea.dst0;
  int* cnt = dir ? ea.cnt1 : ea.cnt0;
  atomicAdd(&cnt[dst[e]], 1);
}

__global__ __launch_bounds__(1024) void scan_kernel(EdgeArgs ea) {
  const int dir = blockIdx.y;
  const int* cnt = dir ? ea.cnt1 : ea.cnt0;
  int* indptr = dir ? ea.indptr1 : ea.indptr0;
  int* fill = dir ? ea.fill1 : ea.fill0;
  const int n = dir ? ea.nd1 : ea.nd0;
  __shared__ int sd[1024];
  const int t = threadIdx.x;
  const int chunk = (n + 1023) >> 10;
  const int start = t * chunk;
  const int end = (start + chunk < n) ? (start + chunk) : n;
  int sum = 0;
  for (int i = start; i < end; ++i) sum += cnt[i];
  sd[t] = sum;
  __syncthreads();
  for (int off = 1; off < 1024; off <<= 1) {
    int v = (t >= off) ? sd[t - off] : 0;
    __syncthreads();
    sd[t] += v;
    __syncthreads();
  }
  int run = sd[t] - sum;   // exclusive prefix
  for (int i = start; i < end; ++i) { indptr[i] = run; fill[i] = run; run += cnt[i]; }
  if (t == 0) indptr[n] = ea.E;
}

__global__ void scatter_kernel(EdgeArgs ea) {
  const int dir = blockIdx.y;
  const int e = blockIdx.x * 256 + threadIdx.x;
  if (e >= ea.E) return;
  const int* dst = dir ? ea.dst1 : ea.dst0;
  const int* src = dir ? ea.src1 : ea.src0;
  int* fill = dir ? ea.fill1 : ea.fill0;
  int* esrc = dir ? ea.esrc1 : ea.esrc0;
  const int pos = atomicAdd(&fill[dst[e]], 1);
  esrc[pos] = src[e];
}

// ---------------------------------------------------------------------------
// mean aggregation: one wave per dst row; lane covers 8 bf16 (16B).
// 4-edge unroll -> 4 independent 1KB gathers in flight per wave.
// ---------------------------------------------------------------------------
__device__ __forceinline__ void acc8(float* a, uint4 u) {
  a[0] += bf2f((unsigned short)(u.x & 0xffff)); a[1] += bf2f((unsigned short)(u.x >> 16));
  a[2] += bf2f((unsigned short)(u.y & 0xffff)); a[3] += bf2f((unsigned short)(u.y >> 16));
  a[4] += bf2f((unsigned short)(u.z & 0xffff)); a[5] += bf2f((unsigned short)(u.z >> 16));
  a[6] += bf2f((unsigned short)(u.w & 0xffff)); a[7] += bf2f((unsigned short)(u.w >> 16));
}

__global__ __launch_bounds__(256) void agg_kernel(
    const ushort_t* __restrict__ hsrc, const int* __restrict__ indptr,
    const int* __restrict__ esrc, ushort_t* __restrict__ out, int ndst)
{
  const int widx = blockIdx.x * 4 + (threadIdx.x >> 6);
  const int l = threadIdx.x & 63;
  if (widx >= ndst) return;
  const int s = indptr[widx], e = indptr[widx + 1];
  float a[8] = {0.f, 0.f, 0.f, 0.f, 0.f, 0.f, 0.f, 0.f};
  int i = s;
  for (; i + 3 < e; i += 4) {
    const int r0 = esrc[i], r1 = esrc[i + 1], r2 = esrc[i + 2], r3 = esrc[i + 3];
    const uint4 u0 = *(const uint4*)(hsrc + (size_t)r0 * 512 + l * 8);
    const uint4 u1 = *(const uint4*)(hsrc + (size_t)r1 * 512 + l * 8);
    const uint4 u2 = *(const uint4*)(hsrc + (size_t)r2 * 512 + l * 8);
    const uint4 u3 = *(const uint4*)(hsrc + (size_t)r3 * 512 + l * 8);
    acc8(a, u0); acc8(a, u1); acc8(a, u2); acc8(a, u3);
  }
  for (; i < e; ++i) {
    const uint4 u = *(const uint4*)(hsrc + (size_t)esrc[i] * 512 + l * 8);
    acc8(a, u);
  }
  const int deg = e - s;
  const float sc = 1.0f / (float)(deg > 1 ? deg : 1);
  uint4 o;
  o.x = pack2(a[0] * sc, a[1] * sc); o.y = pack2(a[2] * sc, a[3] * sc);
  o.z = pack2(a[4] * sc, a[5] * sc); o.w = pack2(a[6] * sc, a[7] * sc);
  *(uint4*)(out + (size_t)widx * 512 + l * 8) = o;
}

// ---------------------------------------------------------------------------
// weight casts: y-dim selects matrix (0=Wn, 1=Ws direct; 2=Wu transpose-cast)
// ---------------------------------------------------------------------------
struct CastArgs { const float* Wn[4]; const float* Ws[4]; const float* Wu[4]; };

__global__ void cast_all_kernel(CastArgs ca, ushort_t* __restrict__ WnWs,
                                ushort_t* __restrict__ WuT)
{
  const int sage = blockIdx.z;
  const int type = blockIdx.y;
  const int idx = blockIdx.x * 256 + threadIdx.x;
  if (type < 2) {
    if (idx >= 512 * 512) return;
    const float* src = type == 0 ? ca.Wn[sage] : ca.Ws[sage];
    WnWs[(size_t)sage * 524288 + type * 262144 + idx] = f2bf(src[idx]);
  } else {
    if (idx >= 1024 * 512) return;
    const int k = idx >> 9, n = idx & 511;     // read Wu[k][n] coalesced
    WuT[(size_t)sage * 524288 + (size_t)n * 1024 + k] = f2bf(ca.Wu[sage][idx]);
  }
}

struct BiasArgs { const float* bn[4]; const float* bs[4];
                  const float* Wu[4]; const float* bu[4]; };

__global__ void bias_fold_kernel(BiasArgs ba, float* __restrict__ cf) {
  const int sage = blockIdx.y;
  const int n = blockIdx.x * 256 + threadIdx.x;   // grid.x = 2 -> n in [0,512)
  const float* Wu = ba.Wu[sage];
  const float* bn = ba.bn[sage];
  const float* bs = ba.bs[sage];
  float s = ba.bu[sage][n];
  for (int j = 0; j < 512; ++j)
    s += bn[j] * Wu[(size_t)j * 512 + n] + bs[j] * Wu[(size_t)(512 + j) * 512 + n];
  cf[sage * 512 + n] = s;
}

// ---------------------------------------------------------------------------
extern "C" void kernel_launch(void* const* d_in, const int* in_sizes, int n_in,
                              void* d_out, int out_size, void* d_ws, size_t ws_size,
                              hipStream_t stream)
{
  const int Dm = 512;
  const int N0 = in_sizes[0] / Dm;              // 100000
  const int N1 = in_sizes[1] / Dm;              // 100000
  const int E  = in_sizes[2] / 2;               // 1000000
  const int NMAX = N0 > N1 ? N0 : N1;
  const int MP = ((NMAX + 127) / 128) * 128;    // 100096
  const int Mtiles = MP / 128;

  auto al = [](size_t x) { return (x + 255) & ~(size_t)255; };
  const size_t BIG = (size_t)MP * 512 * sizeof(ushort_t);   // 102.5 MB

  char* p = (char*)d_ws;
  ushort_t* h0 = (ushort_t*)p; p += BIG;        // lrelu(x_n0) / later agg01'
  ushort_t* h1 = (ushort_t*)p; p += BIG;        // lrelu(x_n1) / later agg10'
  ushort_t* bA = (ushort_t*)p; p += BIG;        // agg01 -> later h0n
  ushort_t* bB = (ushort_t*)p; p += BIG;        // agg10
  ushort_t* bC = (ushort_t*)p; p += BIG;        // h1n
  ushort_t* WnWs = (ushort_t*)p; p += al((size_t)4 * 524288 * 2);
  ushort_t* WuT  = (ushort_t*)p; p += al((size_t)4 * 524288 * 2);
  ushort_t* WfT  = (ushort_t*)p; p += al((size_t)4 * 524288 * 2);
  float* cf = (float*)p; p += al(4 * 512 * sizeof(float));
  char* cnt_base = p;
  int* cnt0 = (int*)p; p += al((size_t)N1 * 4);
  int* cnt1 = (int*)p; p += al((size_t)N0 * 4);
  const size_t cnt_bytes = (size_t)(p - cnt_base);
  int* ip0 = (int*)p; p += al((size_t)(N1 + 1) * 4);
  int* ip1 = (int*)p; p += al((size_t)(N0 + 1) * 4);
  int* fl0 = (int*)p; p += al((size_t)N1 * 4);
  int* fl1 = (int*)p; p += al((size_t)N0 * 4);
  int* es0 = (int*)p; p += al((size_t)E * 4);
  int* es1 = (int*)p; p += al((size_t)E * 4);
  if ((size_t)(p - (char*)d_ws) > ws_size) return;   // fail visibly, no corruption

  const float* x0 = (const float*)d_in[0];
  const float* x1 = (const float*)d_in[1];
  const int* ei01 = (const int*)d_in[2];
  const int* ei10 = (const int*)d_in[3];

  CastArgs ca; BiasArgs ba;
  for (int s = 0; s < 4; ++s) {
    const int base = 4 + 6 * s;   // s0=l1_01, s1=l1_10, s2=l2_01, s3=l2_10
    ca.Wn[s] = (const float*)d_in[base + 0];
    ba.bn[s] = (const float*)d_in[base + 1];
    ca.Ws[s] = (const float*)d_in[base + 2];
    ba.bs[s] = (const float*)d_in[base + 3];
    ca.Wu[s] = (const float*)d_in[base + 4];
    ba.Wu[s] = ca.Wu[s];
    ba.bu[s] = (const float*)d_in[base + 5];
  }

  EdgeArgs ea;
  ea.src0 = ei01; ea.dst0 = ei01 + E;
  ea.src1 = ei10; ea.dst1 = ei10 + E;
  ea.cnt0 = cnt0; ea.cnt1 = cnt1;
  ea.indptr0 = ip0; ea.indptr1 = ip1;
  ea.fill0 = fl0; ea.fill1 = fl1;
  ea.esrc0 = es0; ea.esrc1 = es1;
  ea.E = E; ea.nd0 = N1; ea.nd1 = N0;

  // ---- input prep + CSR build ----
  hipMemsetAsync(cnt_base, 0, cnt_bytes, stream);
  lrelu_cast_kernel<<<dim3((N0 * Dm / 4 + 255) / 256), 256, 0, stream>>>(x0, h0, N0 * Dm / 4);
  lrelu_cast_kernel<<<dim3((N1 * Dm / 4 + 255) / 256), 256, 0, stream>>>(x1, h1, N1 * Dm / 4);
  hist_kernel<<<dim3((E + 255) / 256, 2), 256, 0, stream>>>(ea);
  scan_kernel<<<dim3(1, 2), 1024, 0, stream>>>(ea);
  scatter_kernel<<<dim3((E + 255) / 256, 2), 256, 0, stream>>>(ea);

  // ---- weight folding ----
  cast_all_kernel<<<dim3(2048, 3, 4), 256, 0, stream>>>(ca, WnWs, WuT);
  fold_gemm_kernel<<<dim3(4, 4, 8), 512, 0, stream>>>(WnWs, WuT, WfT);
  bias_fold_kernel<<<dim3(2, 4), 256, 0, stream>>>(ba, cf);

  // ---- layer 1 ----
  agg_kernel<<<dim3((N1 + 3) / 4), 256, 0, stream>>>(h0, ip0, es0, bA, N1); // agg01
  agg_kernel<<<dim3((N0 + 3) / 4), 256, 0, stream>>>(h1, ip1, es1, bB, N0); // agg10

  GemmArgs g;
  g.lda = 512; g.ka0 = 512; g.ldb = 1024; g.Ktiles = 32; g.ldo = 512;
  const int NWG = Mtiles * 4;   // 1-D grid, bn fastest + XCD chunk swizzle
  // o1 = [agg01 | h1] @ Wf(l1_01) -> lrelu -> bC (h1n)
  g.A0 = bA; g.A1 = h1; g.BT = WfT + 0 * 524288; g.bias = cf + 0;
  g.out = bC; g.Mreal = N1;
  gemm_kernel<1><<<dim3(NWG), 512, 0, stream>>>(g);
  // o0 = [agg10 | h0] @ Wf(l1_10) -> lrelu -> bA (h0n)
  g.A0 = bB; g.A1 = h0; g.BT = WfT + 1 * 524288; g.bias = cf + 512;
  g.out = bA; g.Mreal = N0;
  gemm_kernel<1><<<dim3(NWG), 512, 0, stream>>>(g);

  // ---- layer 2 ----
  agg_kernel<<<dim3((N1 + 3) / 4), 256, 0, stream>>>(bA, ip0, es0, h0, N1); // agg01'
  agg_kernel<<<dim3((N0 + 3) / 4), 256, 0, stream>>>(bC, ip1, es1, h1, N0); // agg10'

  // o1_final = [agg01' | h1n] @ Wf(l2_01) -> d_out + N0*512 (f32)
  g.A0 = h0; g.A1 = bC; g.BT = WfT + 2 * 524288; g.bias = cf + 1024;
  g.out = (float*)d_out + (size_t)N0 * 512; g.Mreal = N1;
  gemm_kernel<0><<<dim3(NWG), 512, 0, stream>>>(g);
  // o0_final = [agg10' | h0n] @ Wf(l2_10) -> d_out (f32)
  g.A0 = h1; g.A1 = bA; g.BT = WfT + 3 * 524288; g.bias = cf + 1536;
  g.out = (float*)d_out; g.Mreal = N0;
  gemm_kernel<0><<<dim3(NWG), 512, 0, stream>>>(g);
}